// Round 4
// baseline (3219.948 us; speedup 1.0000x reference)
//
#include <hip/hip_runtime.h>

#define BATCH_N 16384
#define PPLANE 524288         // 512 rows * 1024 ushorts per packed weight plane
typedef unsigned short ushort_t;
typedef __attribute__((ext_vector_type(4))) float f32x4;
typedef __attribute__((ext_vector_type(8))) short s16x8;

// Cheap truncating hi/lo bf16 split: v ~= hi + lo to ~2^-16 relative.
__device__ inline void split_bf(float f, ushort_t& h, ushort_t& l) {
    unsigned u = __float_as_uint(f);
    h = (ushort_t)(u >> 16);
    float fh = __uint_as_float(u & 0xFFFF0000u);
    float r = f - fh;
    l = (ushort_t)(__float_as_uint(r) >> 16);
}

// ---------------------------------------------------------------------------
// Weight packing: fp32 row (512) -> packed swizzled hi|lo row (1024 ushorts).
// Row layout: 16 k-chunks (32 k each) x 8 slots x 8 ushorts (16B).
// Slot s of chunk kc holds: c = s ^ (row&7); c<4 -> hi[k=kc*32+c*8 ..+8),
// else lo[k=kc*32+(c-4)*8 ..+8). This IS the LDS image the GEMM wants, so
// GEMM-side B staging is a linear copy. One wave per row; lane handles 8 k.
// addI: pack (W + I) -- folds the "+xw" window residual into the GEMM.
// ---------------------------------------------------------------------------
__global__ __launch_bounds__(256) void pack_w_k(
    const float* __restrict__ src, ushort_t* __restrict__ dst, int nrows,
    int addI)
{
    const int lane = threadIdx.x & 63;
    const int row = blockIdx.x * 4 + (threadIdx.x >> 6);
    if (row >= nrows) return;
    const int r = row & 7;
    const int kc = lane >> 2, c = lane & 3;
    const float* s = src + (size_t)row * 512 + kc * 32 + c * 8;
    f32x4 v0 = *(const f32x4*)s;
    f32x4 v1 = *(const f32x4*)(s + 4);
    if (addI) {
        const int d = row & 511;               // within-plane output index
        const int kbase = kc * 32 + c * 8;
#pragma unroll
        for (int e = 0; e < 4; ++e) {
            if (kbase + e == d)     v0[e] += 1.0f;
            if (kbase + 4 + e == d) v1[e] += 1.0f;
        }
    }
    s16x8 hv, lv;
    ushort_t h, l;
#pragma unroll
    for (int e = 0; e < 4; ++e) { split_bf(v0[e], h, l); hv[e] = (short)h; lv[e] = (short)l; }
#pragma unroll
    for (int e = 0; e < 4; ++e) { split_bf(v1[e], h, l); hv[4 + e] = (short)h; lv[4 + e] = (short)l; }
    ushort_t* base = dst + (size_t)row * 1024 + kc * 64;
    *(s16x8*)&base[(c ^ r) * 8]       = hv;
    *(s16x8*)&base[((4 + c) ^ r) * 8] = lv;
}

// ---------------------------------------------------------------------------
// Split-bf16 MFMA GEMM, tile 128x128, BK=32, 4 waves of 64x64.
// out[m][n] = sum_k A[m][k] * W[n][k]  (+ bias / logits epilogue)
// Pipelined 2-stage schedule, double-buffered LDS, ONE barrier per K-step:
//   iter t: [vm-wait; convert+ds_write buf[cur]] -> __syncthreads ->
//           [issue G(t+1)] -> [ds_read + MFMA on buf[cur]] ; cur ^= 1
// At the barrier nothing is in flight (G(t) consumed, G(t+1) not yet issued)
// so the implicit vmcnt(0) drain is free; G(t+1) latency hides under MFMA.
// Hazard: W(t+1) vs R(t-1) same buffer separated by barrier(t); each wave's
// ds_reads complete before its own MFMA (lgkmcnt) hence before the barrier.
// LDS image per row (64 ushorts = 128B): slot s holds chunk s^(row&7)
// (chunks 0-3 = hi, 4-7 = lo); reads XOR by (l15&7) -> conflict-free
// (verified round 3: SQ_LDS_BANK_CONFLICT == 0).
// NOTE __launch_bounds__(256,2): 64 KB LDS caps at 2 blocks/CU anyway; the
// 256-VGPR budget guarantees acc[4][4] + 32 prefetch regs never spill
// (round-1 disaster: bound 5 -> acc spilled, WRITE_SIZE 36MB->4.6GB).
// ---------------------------------------------------------------------------
template <int EPI>
__global__ __launch_bounds__(256, 2) void mfma_gemm_k(
    const float* __restrict__ A, int lda, int aoff,
    const ushort_t* __restrict__ Wpk,
    const float* __restrict__ bias, float* __restrict__ outp,
    const float* __restrict__ q, float* __restrict__ logits)
{
    __shared__ __align__(16) ushort_t As[2][128 * 64];
    __shared__ __align__(16) ushort_t Bs[2][128 * 64];

    const int t = threadIdx.x;
    const int lane = t & 63, wave = t >> 6;
    const int wm = (wave >> 1) * 64, wn = (wave & 1) * 64;
    const int quad = lane >> 4, l15 = lane & 15;
    const size_t b0 = (size_t)blockIdx.x * 128;
    const int n0 = blockIdx.y * 128;
    int p = 0;
    if (EPI == 1) {
        p = blockIdx.z;
        Wpk += (size_t)PPLANE * p;
        aoff += p * 512;
    }

    // ---- A staging geometry: row = t&127 (fixed); chunks c = (t>>7) + 2u
    const int arow = t & 127;
    const int rr = arow & 7;
    const float* aptr = A + (b0 + arow) * (size_t)lda + aoff + (t >> 7) * 8;
    const int awo_hi[2] = { arow * 64 + (((t >> 7) + 0) ^ rr) * 8,
                            arow * 64 + (((t >> 7) + 2) ^ rr) * 8 };
    const int awo_lo[2] = { arow * 64 + ((4 + (t >> 7) + 0) ^ rr) * 8,
                            arow * 64 + ((4 + (t >> 7) + 2) ^ rr) * 8 };

    // read-side swizzled within-row offsets (ushort units); row&7 == l15&7.
    const int xr = (l15 & 7) << 3;
    const int offh = (quad * 8) ^ xr;          // hi chunk
    const int offl = (32 + quad * 8) ^ xr;     // lo chunk

    f32x4 acc[4][4] = {};

    // ---- prologue: G(0)
    f32x4 av[4];
    s16x8 bv[4];
#pragma unroll
    for (int u = 0; u < 2; ++u) {
        av[2 * u]     = *(const f32x4*)(aptr + u * 16);
        av[2 * u + 1] = *(const f32x4*)(aptr + u * 16 + 4);
    }
#pragma unroll
    for (int u = 0; u < 4; ++u) {
        const int f = t + 256 * u;                       // 0..1023
        bv[u] = *(const s16x8*)&Wpk[(size_t)(n0 + (f >> 3)) * 1024 + (f & 7) * 8];
    }

#pragma unroll 2
    for (int kc = 0; kc < 16; ++kc) {
        const int cur = kc & 1;
        // ---- W(kc): A split to hi/lo, swizzled b128 writes; B linear b128
#pragma unroll
        for (int u = 0; u < 2; ++u) {
            s16x8 hv, lv;
            ushort_t h, l;
#pragma unroll
            for (int e = 0; e < 4; ++e) {
                split_bf(av[2 * u][e], h, l); hv[e] = (short)h; lv[e] = (short)l;
            }
#pragma unroll
            for (int e = 0; e < 4; ++e) {
                split_bf(av[2 * u + 1][e], h, l); hv[4 + e] = (short)h; lv[4 + e] = (short)l;
            }
            *(s16x8*)&As[cur][awo_hi[u]] = hv;
            *(s16x8*)&As[cur][awo_lo[u]] = lv;
        }
#pragma unroll
        for (int u = 0; u < 4; ++u) {
            const int f = t + 256 * u;
            *(s16x8*)&Bs[cur][f * 8] = bv[u];
        }
        __syncthreads();
        // ---- G(kc+1): issue next-tile loads (consumed next iter after MFMA)
        if (kc + 1 < 16) {
#pragma unroll
            for (int u = 0; u < 2; ++u) {
                av[2 * u]     = *(const f32x4*)(aptr + (kc + 1) * 32 + u * 16);
                av[2 * u + 1] = *(const f32x4*)(aptr + (kc + 1) * 32 + u * 16 + 4);
            }
#pragma unroll
            for (int u = 0; u < 4; ++u) {
                const int f = t + 256 * u;
                bv[u] = *(const s16x8*)&Wpk[(size_t)(n0 + (f >> 3)) * 1024
                                            + (kc + 1) * 64 + (f & 7) * 8];
            }
        }
        // ---- R(kc) + MFMA: 16 tiles x 3 split-products
        s16x8 ah[4], alo[4];
#pragma unroll
        for (int i = 0; i < 4; ++i) {
            ah[i]  = *(const s16x8*)&As[cur][(wm + i * 16 + l15) * 64 + offh];
            alo[i] = *(const s16x8*)&As[cur][(wm + i * 16 + l15) * 64 + offl];
        }
#pragma unroll
        for (int j = 0; j < 4; ++j) {
            const s16x8 bh = *(const s16x8*)&Bs[cur][(wn + j * 16 + l15) * 64 + offh];
            const s16x8 bl = *(const s16x8*)&Bs[cur][(wn + j * 16 + l15) * 64 + offl];
#pragma unroll
            for (int i = 0; i < 4; ++i) {
                acc[i][j] = __builtin_amdgcn_mfma_f32_16x16x32_bf16(ah[i], bh, acc[i][j], 0, 0, 0);
                acc[i][j] = __builtin_amdgcn_mfma_f32_16x16x32_bf16(ah[i], bl, acc[i][j], 0, 0, 0);
                acc[i][j] = __builtin_amdgcn_mfma_f32_16x16x32_bf16(alo[i], bh, acc[i][j], 0, 0, 0);
            }
        }
    }

    if (EPI == 0) {
#pragma unroll
        for (int i = 0; i < 4; ++i) {
            const int gm0 = (int)b0 + wm + i * 16 + quad * 4;
#pragma unroll
            for (int j = 0; j < 4; ++j) {
                const int gn = n0 + wn + j * 16 + l15;
                const float bvs = bias[gn];
#pragma unroll
                for (int r = 0; r < 4; ++r)
                    outp[(size_t)(gm0 + r) * 512 + gn] = acc[i][j][r] + bvs;
            }
        }
    } else {
        float rp[4][4] = {};
#pragma unroll
        for (int i = 0; i < 4; ++i) {
            const int gm0 = (int)b0 + wm + i * 16 + quad * 4;
#pragma unroll
            for (int j = 0; j < 4; ++j) {
                const int gn = n0 + wn + j * 16 + l15;
                const float bvs = bias[(size_t)p * 512 + gn];
#pragma unroll
                for (int r = 0; r < 4; ++r)
                    rp[i][r] += (acc[i][j][r] + bvs) * q[(size_t)(gm0 + r) * 512 + gn];
            }
        }
#pragma unroll
        for (int m = 1; m < 16; m <<= 1)
#pragma unroll
            for (int i = 0; i < 4; ++i)
#pragma unroll
                for (int r = 0; r < 4; ++r)
                    rp[i][r] += __shfl_xor(rp[i][r], m, 64);
        if (l15 == 0) {
#pragma unroll
            for (int i = 0; i < 4; ++i) {
                const int gm0 = (int)b0 + wm + i * 16 + quad * 4;
#pragma unroll
                for (int r = 0; r < 4; ++r)
                    atomicAdd(&logits[(size_t)(gm0 + r) * 9 + p], rp[i][r]);
            }
        }
    }
}

// ---------------------------------------------------------------------------
// softmax over 9 logits; cent = sum_p a_p x[b,p,:];
// mode 0: out = l2norm(cent)
// mode 1: out = l2norm(cent + x[b,8,:])   (final)
// ---------------------------------------------------------------------------
__global__ __launch_bounds__(256) void softmax_cent_k(
    const float* __restrict__ x, const float* __restrict__ logits,
    float* __restrict__ outp, int mode)
{
    const int lane = threadIdx.x & 63;
    const size_t b = (size_t)blockIdx.x * 4 + (threadIdx.x >> 6);
    float lg[9], m = -1e30f;
#pragma unroll
    for (int p = 0; p < 9; ++p) { lg[p] = logits[b * 9 + p]; m = fmaxf(m, lg[p]); }
    float s = 0.f;
#pragma unroll
    for (int p = 0; p < 9; ++p) { lg[p] = __expf(lg[p] - m); s += lg[p]; }
    const float inv = 1.0f / s;
    f32x4 c[2];
    float ssq = 0.f;
#pragma unroll
    for (int v = 0; v < 2; ++v) {
        f32x4 a = {0.f, 0.f, 0.f, 0.f};
#pragma unroll
        for (int p = 0; p < 9; ++p) {
            const f32x4 xv = ((const f32x4*)&x[(b * 9 + p) * 512])[v * 64 + lane];
            a += lg[p] * xv;
        }
        a *= inv;
        if (mode) a += ((const f32x4*)&x[(b * 9 + 8) * 512])[v * 64 + lane];
        c[v] = a;
        ssq += a[0]*a[0] + a[1]*a[1] + a[2]*a[2] + a[3]*a[3];
    }
#pragma unroll
    for (int off = 32; off > 0; off >>= 1) ssq += __shfl_xor(ssq, off, 64);
    const float invn = 1.0f / fmaxf(sqrtf(ssq), 1e-12f);
#pragma unroll
    for (int v = 0; v < 2; ++v)
        ((f32x4*)&outp[b * 512])[v * 64 + lane] = c[v] * invn;
}

// ---------------------------------------------------------------------------
// ADD=1: dst_row = l2norm(dst_row + src_row)
// ADD=0: dst_row = l2norm(src_row)        (residual pre-folded into weights)
// dst stride in floats, src stride 512.
// ---------------------------------------------------------------------------
__global__ __launch_bounds__(256) void resid_norm_k(
    float* __restrict__ dst, int dstride, const float* __restrict__ src, int add)
{
    const int lane = threadIdx.x & 63;
    const size_t b = (size_t)blockIdx.x * 4 + (threadIdx.x >> 6);
    f32x4* d4 = (f32x4*)&dst[b * (size_t)dstride];
    const f32x4* s4 = (const f32x4*)&src[b * 512];
    f32x4 a[2];
    float ssq = 0.f;
#pragma unroll
    for (int v = 0; v < 2; ++v) {
        a[v] = s4[v * 64 + lane];
        if (add) a[v] += d4[v * 64 + lane];
        ssq += a[v][0]*a[v][0] + a[v][1]*a[v][1] + a[v][2]*a[v][2] + a[v][3]*a[v][3];
    }
#pragma unroll
    for (int off = 32; off > 0; off >>= 1) ssq += __shfl_xor(ssq, off, 64);
    const float invn = 1.0f / fmaxf(sqrtf(ssq), 1e-12f);
#pragma unroll
    for (int v = 0; v < 2; ++v) d4[v * 64 + lane] = a[v] * invn;
}

// ---------------------------------------------------------------------------
extern "C" void kernel_launch(void* const* d_in, const int* in_sizes, int n_in,
                              void* d_out, int out_size, void* d_ws, size_t ws_size,
                              hipStream_t stream) {
    (void)in_sizes; (void)n_in; (void)out_size; (void)ws_size;
    float* x = (float*)d_in[0];   // mutated in place; harness restores per launch
    const float* Wq  = (const float*)d_in[1];
    const float* bq  = (const float*)d_in[2];
    const float* Wk  = (const float*)d_in[3];
    const float* bk  = (const float*)d_in[4];
    const float* Wfw = (const float*)d_in[5];
    const float* bfw = (const float*)d_in[6];
    const float* Wfc = (const float*)d_in[7];
    const float* bfc = (const float*)d_in[8];
    const float* Wqf = (const float*)d_in[9];
    const float* bqf = (const float*)d_in[10];
    const float* Wkf = (const float*)d_in[11];
    const float* bkf = (const float*)d_in[12];
    float* out = (float*)d_out;

    // ws layout: [packed weight planes | q | cent(=tmp) | y | logits]
    ushort_t* wpk = (ushort_t*)d_ws;
    float* fbuf   = (float*)(wpk + (size_t)67 * PPLANE);
    float* q      = fbuf;                          // B*512
    float* cent   = q    + (size_t)BATCH_N * 512;  // B*512 (reused as window tmp)
    float* y      = cent + (size_t)BATCH_N * 512;  // B*512
    float* logits = y    + (size_t)BATCH_N * 512;  // B*9
    float* tmp    = cent;

    // plane offsets (units of PPLANE): Wq 0(3), Wk 3(27), Wfw 30(24), Wfc 54(3),
    // Wqf 57(1), Wkf 58(9)
    const size_t OWq = 0, OWk = 3, OWfw = 30, OWfc = 54, OWqf = 57, OWkf = 58;

    // ---- one-time (per launch) weight packing into swizzled LDS image
    // Wfw gets +I: window residual folded into the GEMM.
    struct { const float* s; size_t off; int cnt; int addI; } cv[6] = {
        {Wq, OWq, 3, 0}, {Wk, OWk, 27, 0}, {Wfw, OWfw, 24, 1},
        {Wfc, OWfc, 3, 0}, {Wqf, OWqf, 1, 0}, {Wkf, OWkf, 9, 0}};
    for (int i = 0; i < 6; ++i) {
        const int nrows = cv[i].cnt * 512;
        pack_w_k<<<nrows / 4, 256, 0, stream>>>(
            cv[i].s, wpk + cv[i].off * PPLANE, nrows, cv[i].addI);
    }

    const dim3 gemm_grid(BATCH_N / 128, 4);
    const dim3 log_grid(BATCH_N / 128, 4, 9);
    const int ew_grid = BATCH_N / 4;

    for (int l = 0; l < 3; ++l) {
        // q = x[:,8,:] @ Wq^T + bq
        mfma_gemm_k<0><<<gemm_grid, 256, 0, stream>>>(
            x, 9 * 512, 8 * 512,
            wpk + (OWq + l) * PPLANE,
            bq + l * 512, q, nullptr, nullptr);
        // logits
        hipMemsetAsync(logits, 0, (size_t)BATCH_N * 9 * sizeof(float), stream);
        mfma_gemm_k<1><<<log_grid, 256, 0, stream>>>(
            x, 9 * 512, 0,
            wpk + (OWk + (size_t)l * 9) * PPLANE,
            bk + (size_t)l * 9 * 512, nullptr, q, logits);
        // cent = l2norm(softmax-weighted sum)
        softmax_cent_k<<<ew_grid, 256, 0, stream>>>(x, logits, cent, 0);
        // y = cent @ Wfc^T + bfc
        mfma_gemm_k<0><<<gemm_grid, 256, 0, stream>>>(
            cent, 512, 0,
            wpk + (OWfc + l) * PPLANE,
            bfc + l * 512, y, nullptr, nullptr);
        // x[:,8,:] = l2norm(x[:,8,:] + y)
        resid_norm_k<<<ew_grid, 256, 0, stream>>>(x + 8 * 512, 9 * 512, y, 1);
        // window: per p, tmp = x[:,p,:]@(Wfw[p]+I)^T + bfw[p]; x[:,p,:]=l2norm(tmp)
        for (int p = 0; p < 8; ++p) {
            mfma_gemm_k<0><<<gemm_grid, 256, 0, stream>>>(
                x, 9 * 512, p * 512,
                wpk + (OWfw + (size_t)l * 8 + p) * PPLANE,
                bfw + ((size_t)l * 8 + p) * 512, tmp, nullptr, nullptr);
            resid_norm_k<<<ew_grid, 256, 0, stream>>>(x + p * 512, 9 * 512, tmp, 0);
        }
    }
    // final attention -> out
    mfma_gemm_k<0><<<gemm_grid, 256, 0, stream>>>(
        x, 9 * 512, 8 * 512, wpk + OWqf * PPLANE,
        bqf, q, nullptr, nullptr);
    hipMemsetAsync(logits, 0, (size_t)BATCH_N * 9 * sizeof(float), stream);
    mfma_gemm_k<1><<<log_grid, 256, 0, stream>>>(
        x, 9 * 512, 0, wpk + OWkf * PPLANE,
        bkf, nullptr, q, logits);
    softmax_cent_k<<<ew_grid, 256, 0, stream>>>(x, logits, out, 1);
}

// Round 5
// 2807.220 us; speedup vs baseline: 1.1470x; 1.1470x over previous
//
#include <hip/hip_runtime.h>

#define BATCH_N 16384
#define PPLANE 524288         // 512 rows * 1024 ushorts per packed weight plane
typedef unsigned short ushort_t;
typedef __attribute__((ext_vector_type(4))) float f32x4;
typedef __attribute__((ext_vector_type(8))) short s16x8;

// Cheap truncating hi/lo bf16 split: v ~= hi + lo to ~2^-16 relative.
__device__ inline void split_bf(float f, ushort_t& h, ushort_t& l) {
    unsigned u = __float_as_uint(f);
    h = (ushort_t)(u >> 16);
    float fh = __uint_as_float(u & 0xFFFF0000u);
    float r = f - fh;
    l = (ushort_t)(__float_as_uint(r) >> 16);
}
__device__ inline float recon_bf(short h, short l) {
    return __uint_as_float(((unsigned)(ushort_t)h) << 16) +
           __uint_as_float(((unsigned)(ushort_t)l) << 16);
}
__device__ inline void pack8(const f32x4& v0, const f32x4& v1, s16x8& hv, s16x8& lv) {
    ushort_t h, l;
#pragma unroll
    for (int e = 0; e < 4; ++e) { split_bf(v0[e], h, l); hv[e] = (short)h; lv[e] = (short)l; }
#pragma unroll
    for (int e = 0; e < 4; ++e) { split_bf(v1[e], h, l); hv[4 + e] = (short)h; lv[4 + e] = (short)l; }
}

// ---------------------------------------------------------------------------
// Packed row format (shared by weights and activations): 512 values ->
// 1024 ushorts = 16 k-chunks x 8 slots x 8 ushorts (16B). Slot s of chunk kc
// holds data chunk c = s ^ (key&7): c<4 -> hi[k=kc*32+c*8..+8), else lo.
// key = weight row n, or batch index b (activations). This IS the LDS image
// the GEMM wants -> GEMM staging is a LINEAR copy with zero convert VALU.
// ---------------------------------------------------------------------------

// Weight packing; addI folds "+x" residual (window path) into the GEMM.
__global__ __launch_bounds__(256) void pack_w_k(
    const float* __restrict__ src, ushort_t* __restrict__ dst, int nrows,
    int addI)
{
    const int lane = threadIdx.x & 63;
    const int row = blockIdx.x * 4 + (threadIdx.x >> 6);
    if (row >= nrows) return;
    const int r = row & 7;
    const int kc = lane >> 2, c = lane & 3;
    const float* s = src + (size_t)row * 512 + lane * 8;
    f32x4 v0 = *(const f32x4*)s;
    f32x4 v1 = *(const f32x4*)(s + 4);
    if (addI) {
        const int d = row & 511;
        const int kbase = lane * 8;
#pragma unroll
        for (int e = 0; e < 4; ++e) {
            if (kbase + e == d)     v0[e] += 1.0f;
            if (kbase + 4 + e == d) v1[e] += 1.0f;
        }
    }
    s16x8 hv, lv;
    pack8(v0, v1, hv, lv);
    ushort_t* base = dst + (size_t)row * 1024 + kc * 64;
    *(s16x8*)&base[(c ^ r) * 8]       = hv;
    *(s16x8*)&base[((4 + c) ^ r) * 8] = lv;
}

// In-place x fp32 -> packed image. One wave per row; store data depends on
// the same wave's loads (true reg dependence) so the in-place transmute is
// ordered; rows are disjoint across waves.
__global__ __launch_bounds__(256) void pack_x_k(float* __restrict__ xf, int nrows)
{
    const int lane = threadIdx.x & 63;
    const int row = blockIdx.x * 4 + (threadIdx.x >> 6);   // row = b*9 + p
    if (row >= nrows) return;
    const int b = row / 9;
    const int r = b & 7;                                   // key on batch index
    const int kc = lane >> 2, c = lane & 3;
    const float* s = xf + (size_t)row * 512 + lane * 8;
    const f32x4 v0 = *(const f32x4*)s;
    const f32x4 v1 = *(const f32x4*)(s + 4);
    s16x8 hv, lv;
    pack8(v0, v1, hv, lv);
    ushort_t* base = (ushort_t*)xf + (size_t)row * 1024 + kc * 64;
    *(s16x8*)&base[(c ^ r) * 8]       = hv;
    *(s16x8*)&base[((4 + c) ^ r) * 8] = lv;
}

// ---------------------------------------------------------------------------
// Split-bf16 MFMA GEMM, tile 128x128, BK=32, 4 waves of 64x64.
// out[m][n] = sum_k A[m][k] * W[n][k]  (+ bias / logits epilogue)
// BOTH A and W are pre-packed images -> staging = pure linear b128 copies
// (8 loads + 8 ds_writes/thread/K-step, ZERO convert VALU in the hot loop).
// blockIdx.z: weight plane steps PPLANE, bias steps 512, A offset steps
// astep_us; EPI=0 out steps BATCH_N*512, EPI=1 dots with q -> logits[b*9+z].
// MFMA 16x16x32 layouts (verified):
//   A/B frag: row/col = lane&15, k = (lane>>4)*8 + j
//   C/D:      col = lane&15, row = (lane>>4)*4 + reg
// Reads XOR by (l15&7): conflict-free (verified round 3: conflicts == 0).
// lds_pad: 40 KB/block -> 4 blocks/CU, replicating the best-measured
// (round-0) occupancy point; round-3's 5 blocks/CU measured slower.
// NOTE __launch_bounds__(256,3): bound >=4 spills acc (round-1: WRITE_SIZE
// 36MB->4.6GB, 5x slowdown). Do not raise.
// ---------------------------------------------------------------------------
template <int EPI>
__global__ __launch_bounds__(256, 3) void mfma_gemm_k(
    const ushort_t* __restrict__ Ap, int lda_us, int aoff_us, int astep_us,
    const ushort_t* __restrict__ Wpk, const float* __restrict__ bias,
    float* __restrict__ outp, const float* __restrict__ q,
    float* __restrict__ logits)
{
    __shared__ __align__(16) ushort_t As[128 * 64];
    __shared__ __align__(16) ushort_t Bs[128 * 64];
    __shared__ ushort_t lds_pad[4096];

    const int t = threadIdx.x;
    if (lda_us == 0) lds_pad[t] = 0;     // never true; keeps the pad allocated
    const int lane = t & 63, wave = t >> 6;
    const int wm = (wave >> 1) * 64, wn = (wave & 1) * 64;
    const int quad = lane >> 4, l15 = lane & 15;
    const size_t b0 = (size_t)blockIdx.x * 128;
    const int n0 = blockIdx.y * 128;
    const int z = blockIdx.z;
    Wpk += (size_t)PPLANE * z;
    aoff_us += z * astep_us;
    bias += z * 512;
    if (EPI == 0) outp += (size_t)z * BATCH_N * 512;

    // staging geometry: id = t + 256u -> row id>>3, slot id&7 (linear both sides)
    const ushort_t* aptr[4];
    const ushort_t* bptr[4];
#pragma unroll
    for (int u = 0; u < 4; ++u) {
        const int id = t + 256 * u;
        aptr[u] = Ap + (b0 + (id >> 3)) * (size_t)lda_us + aoff_us + (id & 7) * 8;
        bptr[u] = Wpk + (size_t)(n0 + (id >> 3)) * 1024 + (id & 7) * 8;
    }

    const int xr = (l15 & 7) << 3;
    const int offh = (quad * 8) ^ xr;          // hi chunk
    const int offl = (32 + quad * 8) ^ xr;     // lo chunk

    f32x4 acc[4][4] = {};

    for (int kc = 0; kc < 16; ++kc) {
        // ---- global prefetch into registers (overlaps prev MFMA tail)
        s16x8 avv[4], bvv[4];
#pragma unroll
        for (int u = 0; u < 4; ++u) {
            avv[u] = *(const s16x8*)(aptr[u] + kc * 64);
            bvv[u] = *(const s16x8*)(bptr[u] + kc * 64);
        }
        __syncthreads();    // prev-iter LDS reads done
        // ---- stage: 8 linear ds_write_b128 (conflict-free)
#pragma unroll
        for (int u = 0; u < 4; ++u) {
            *(s16x8*)&As[t * 8 + 2048 * u] = avv[u];
            *(s16x8*)&Bs[t * 8 + 2048 * u] = bvv[u];
        }
        __syncthreads();
        // ---- MFMA: 16 tiles x 3 split-products
        s16x8 ah[4], alo[4];
#pragma unroll
        for (int i = 0; i < 4; ++i) {
            ah[i]  = *(const s16x8*)&As[(wm + i * 16 + l15) * 64 + offh];
            alo[i] = *(const s16x8*)&As[(wm + i * 16 + l15) * 64 + offl];
        }
#pragma unroll
        for (int j = 0; j < 4; ++j) {
            const s16x8 bh = *(const s16x8*)&Bs[(wn + j * 16 + l15) * 64 + offh];
            const s16x8 bl = *(const s16x8*)&Bs[(wn + j * 16 + l15) * 64 + offl];
#pragma unroll
            for (int i = 0; i < 4; ++i) {
                acc[i][j] = __builtin_amdgcn_mfma_f32_16x16x32_bf16(ah[i], bh, acc[i][j], 0, 0, 0);
                acc[i][j] = __builtin_amdgcn_mfma_f32_16x16x32_bf16(ah[i], bl, acc[i][j], 0, 0, 0);
                acc[i][j] = __builtin_amdgcn_mfma_f32_16x16x32_bf16(alo[i], bh, acc[i][j], 0, 0, 0);
            }
        }
    }

    if (EPI == 0) {
#pragma unroll
        for (int i = 0; i < 4; ++i) {
            const int gm0 = (int)b0 + wm + i * 16 + quad * 4;
#pragma unroll
            for (int j = 0; j < 4; ++j) {
                const int gn = n0 + wn + j * 16 + l15;
                const float bvs = bias[gn];
#pragma unroll
                for (int r = 0; r < 4; ++r)
                    outp[(size_t)(gm0 + r) * 512 + gn] = acc[i][j][r] + bvs;
            }
        }
    } else {
        float rp[4][4] = {};
#pragma unroll
        for (int i = 0; i < 4; ++i) {
            const int gm0 = (int)b0 + wm + i * 16 + quad * 4;
#pragma unroll
            for (int j = 0; j < 4; ++j) {
                const int gn = n0 + wn + j * 16 + l15;
                const float bvs = bias[gn];
#pragma unroll
                for (int r = 0; r < 4; ++r)
                    rp[i][r] += (acc[i][j][r] + bvs) * q[(size_t)(gm0 + r) * 512 + gn];
            }
        }
#pragma unroll
        for (int m = 1; m < 16; m <<= 1)
#pragma unroll
            for (int i = 0; i < 4; ++i)
#pragma unroll
                for (int r = 0; r < 4; ++r)
                    rp[i][r] += __shfl_xor(rp[i][r], m, 64);
        if (l15 == 0) {
#pragma unroll
            for (int i = 0; i < 4; ++i) {
                const int gm0 = (int)b0 + wm + i * 16 + quad * 4;
#pragma unroll
                for (int r = 0; r < 4; ++r)
                    atomicAdd(&logits[(size_t)(gm0 + r) * 9 + z], rp[i][r]);
            }
        }
    }
}

// ---------------------------------------------------------------------------
// softmax over 9 logits; cent = sum_p a_p x[b,p,:]  (x read from packed image)
// mode 0: centp = packed(l2norm(cent))
// mode 1: out  = fp32 l2norm(cent + x[b,8,:])   (final)
// One wave per batch row; lane owns cols [lane*8, lane*8+8).
// ---------------------------------------------------------------------------
__global__ __launch_bounds__(256) void softmax_cent_k(
    const ushort_t* __restrict__ xp, const float* __restrict__ logits,
    ushort_t* __restrict__ centp, float* __restrict__ outp, int mode)
{
    const int lane = threadIdx.x & 63;
    const size_t b = (size_t)blockIdx.x * 4 + (threadIdx.x >> 6);
    float lg[9], m = -1e30f;
#pragma unroll
    for (int p = 0; p < 9; ++p) { lg[p] = logits[b * 9 + p]; m = fmaxf(m, lg[p]); }
    float s = 0.f;
#pragma unroll
    for (int p = 0; p < 9; ++p) { lg[p] = __expf(lg[p] - m); s += lg[p]; }
    const float inv = 1.0f / s;

    const int kc = lane >> 2, c = lane & 3, r = (int)b & 7;
    const int oh = kc * 64 + ((c ^ r) * 8);
    const int ol = kc * 64 + (((4 + c) ^ r) * 8);

    float a[8] = {0.f, 0.f, 0.f, 0.f, 0.f, 0.f, 0.f, 0.f};
    s16x8 h8, l8;
#pragma unroll
    for (int p = 0; p < 9; ++p) {
        const ushort_t* row = xp + (b * 9 + p) * 1024;
        const s16x8 hv = *(const s16x8*)&row[oh];
        const s16x8 lv = *(const s16x8*)&row[ol];
        if (p == 8) { h8 = hv; l8 = lv; }
#pragma unroll
        for (int e = 0; e < 8; ++e) a[e] += lg[p] * recon_bf(hv[e], lv[e]);
    }
#pragma unroll
    for (int e = 0; e < 8; ++e) a[e] *= inv;
    if (mode) {
#pragma unroll
        for (int e = 0; e < 8; ++e) a[e] += recon_bf(h8[e], l8[e]);
    }
    float ssq = 0.f;
#pragma unroll
    for (int e = 0; e < 8; ++e) ssq += a[e] * a[e];
#pragma unroll
    for (int off = 32; off > 0; off >>= 1) ssq += __shfl_xor(ssq, off, 64);
    const float invn = 1.0f / fmaxf(sqrtf(ssq), 1e-12f);
#pragma unroll
    for (int e = 0; e < 8; ++e) a[e] *= invn;

    if (mode) {
        f32x4 o0 = {a[0], a[1], a[2], a[3]};
        f32x4 o1 = {a[4], a[5], a[6], a[7]};
        *(f32x4*)&outp[b * 512 + lane * 8]     = o0;
        *(f32x4*)&outp[b * 512 + lane * 8 + 4] = o1;
    } else {
        f32x4 v0 = {a[0], a[1], a[2], a[3]};
        f32x4 v1 = {a[4], a[5], a[6], a[7]};
        s16x8 hv, lv;
        pack8(v0, v1, hv, lv);
        ushort_t* dc = centp + b * 1024;
        *(s16x8*)&dc[oh] = hv;
        *(s16x8*)&dc[ol] = lv;
    }
}

// ---------------------------------------------------------------------------
// resid+norm on packed x, batched over blockIdx.y slices:
// slice = slice0 + blockIdx.y; src fp32 [z][b][512].
// add=1: xp[:,slice,:] = packed(l2norm(recon(xp[:,slice,:]) + src))
// add=0: xp[:,slice,:] = packed(l2norm(src))   (residual folded into weights)
// ---------------------------------------------------------------------------
__global__ __launch_bounds__(256) void resid_norm_k(
    ushort_t* __restrict__ xp, int slice0, const float* __restrict__ src, int add)
{
    const int lane = threadIdx.x & 63;
    const size_t b = (size_t)blockIdx.x * 4 + (threadIdx.x >> 6);
    const int z = blockIdx.y;
    ushort_t* drow = xp + (b * 9 + (size_t)(slice0 + z)) * 1024;
    const float* srow = src + ((size_t)z * BATCH_N + b) * 512 + lane * 8;
    const int kc = lane >> 2, c = lane & 3, r = (int)b & 7;
    const int oh = kc * 64 + ((c ^ r) * 8);
    const int ol = kc * 64 + (((4 + c) ^ r) * 8);

    f32x4 v0 = *(const f32x4*)srow;
    f32x4 v1 = *(const f32x4*)(srow + 4);
    if (add) {
        const s16x8 hv = *(const s16x8*)&drow[oh];
        const s16x8 lv = *(const s16x8*)&drow[ol];
#pragma unroll
        for (int e = 0; e < 4; ++e) {
            v0[e] += recon_bf(hv[e], lv[e]);
            v1[e] += recon_bf(hv[4 + e], lv[4 + e]);
        }
    }
    float ssq = v0[0]*v0[0] + v0[1]*v0[1] + v0[2]*v0[2] + v0[3]*v0[3]
              + v1[0]*v1[0] + v1[1]*v1[1] + v1[2]*v1[2] + v1[3]*v1[3];
#pragma unroll
    for (int off = 32; off > 0; off >>= 1) ssq += __shfl_xor(ssq, off, 64);
    const float invn = 1.0f / fmaxf(sqrtf(ssq), 1e-12f);
    v0 *= invn; v1 *= invn;
    s16x8 hv, lv;
    pack8(v0, v1, hv, lv);
    *(s16x8*)&drow[oh] = hv;
    *(s16x8*)&drow[ol] = lv;
}

// ---------------------------------------------------------------------------
extern "C" void kernel_launch(void* const* d_in, const int* in_sizes, int n_in,
                              void* d_out, int out_size, void* d_ws, size_t ws_size,
                              hipStream_t stream) {
    (void)in_sizes; (void)n_in; (void)out_size; (void)ws_size;
    float* x = (float*)d_in[0];   // mutated in place; harness restores per launch
    const float* Wq  = (const float*)d_in[1];
    const float* bq  = (const float*)d_in[2];
    const float* Wk  = (const float*)d_in[3];
    const float* bk  = (const float*)d_in[4];
    const float* Wfw = (const float*)d_in[5];
    const float* bfw = (const float*)d_in[6];
    const float* Wfc = (const float*)d_in[7];
    const float* bfc = (const float*)d_in[8];
    const float* Wqf = (const float*)d_in[9];
    const float* bqf = (const float*)d_in[10];
    const float* Wkf = (const float*)d_in[11];
    const float* bkf = (const float*)d_in[12];
    float* out = (float*)d_out;

    ushort_t* xp = (ushort_t*)x;  // packed image lives in x's own buffer

    // ws layout: [packed weight planes (67 MB) | R: 4*B*512 floats | logits]
    // R overlays: q = R[0..B*512) ; centp = R[B*512..2B*512) (as ushort) ;
    // y = R[2B*512..3B*512) ; window tmp (z=4) = R[0..4B*512) — lifetimes
    // are serialized on the stream so the overlay is safe.
    ushort_t* wpk = (ushort_t*)d_ws;
    float* R      = (float*)(wpk + (size_t)67 * PPLANE);
    float* q      = R;
    ushort_t* centp = (ushort_t*)(R + (size_t)BATCH_N * 512);
    float* y      = R + (size_t)2 * BATCH_N * 512;
    float* tmp    = R;
    float* logits = R + (size_t)4 * BATCH_N * 512;

    // plane offsets (units of PPLANE): Wq 0(3), Wk 3(27), Wfw 30(24), Wfc 54(3),
    // Wqf 57(1), Wkf 58(9)
    const size_t OWq = 0, OWk = 3, OWfw = 30, OWfc = 54, OWqf = 57, OWkf = 58;

    // ---- one-time packing: weights (+I fold for Wfw) and x (in place)
    struct { const float* s; size_t off; int cnt; int addI; } cv[6] = {
        {Wq, OWq, 3, 0}, {Wk, OWk, 27, 0}, {Wfw, OWfw, 24, 1},
        {Wfc, OWfc, 3, 0}, {Wqf, OWqf, 1, 0}, {Wkf, OWkf, 9, 0}};
    for (int i = 0; i < 6; ++i) {
        const int nrows = cv[i].cnt * 512;
        pack_w_k<<<nrows / 4, 256, 0, stream>>>(
            cv[i].s, wpk + cv[i].off * PPLANE, nrows, cv[i].addI);
    }
    pack_x_k<<<BATCH_N * 9 / 4, 256, 0, stream>>>(x, BATCH_N * 9);

    const dim3 gemm_grid(BATCH_N / 128, 4, 1);
    const dim3 log_grid(BATCH_N / 128, 4, 9);
    const dim3 win_grid(BATCH_N / 128, 4, 4);
    const dim3 ew_grid(BATCH_N / 4, 1, 1);
    const dim3 ew4_grid(BATCH_N / 4, 4, 1);

    for (int l = 0; l < 3; ++l) {
        // q = x[:,8,:] @ Wq^T + bq
        mfma_gemm_k<0><<<gemm_grid, 256, 0, stream>>>(
            xp, 9 * 1024, 8 * 1024, 0,
            wpk + (OWq + l) * PPLANE, bq + l * 512, q, nullptr, nullptr);
        // logits (z = position)
        hipMemsetAsync(logits, 0, (size_t)BATCH_N * 9 * sizeof(float), stream);
        mfma_gemm_k<1><<<log_grid, 256, 0, stream>>>(
            xp, 9 * 1024, 0, 1024,
            wpk + (OWk + (size_t)l * 9) * PPLANE, bk + (size_t)l * 9 * 512,
            nullptr, q, logits);
        // centp = packed l2norm(softmax-weighted sum)
        softmax_cent_k<<<ew_grid, 256, 0, stream>>>(xp, logits, centp, nullptr, 0);
        // y = cent @ Wfc^T + bfc
        mfma_gemm_k<0><<<gemm_grid, 256, 0, stream>>>(
            centp, 1024, 0, 0,
            wpk + (OWfc + l) * PPLANE, bfc + l * 512, y, nullptr, nullptr);
        // x[:,8,:] = l2norm(x[:,8,:] + y)
        resid_norm_k<<<ew_grid, 256, 0, stream>>>(xp, 8, y, 1);
        // window, batched z=4: tmp[z] = x[:,z0+z,:]@(Wfw+I)^T + bfw;
        // x[:,z0+z,:] = l2norm(tmp[z])
        for (int zb = 0; zb < 8; zb += 4) {
            mfma_gemm_k<0><<<win_grid, 256, 0, stream>>>(
                xp, 9 * 1024, zb * 1024, 1024,
                wpk + (OWfw + (size_t)l * 8 + zb) * PPLANE,
                bfw + ((size_t)l * 8 + zb) * 512, tmp, nullptr, nullptr);
            resid_norm_k<<<ew4_grid, 256, 0, stream>>>(xp, zb, tmp, 0);
        }
    }
    // final attention -> out
    mfma_gemm_k<0><<<gemm_grid, 256, 0, stream>>>(
        xp, 9 * 1024, 8 * 1024, 0,
        wpk + OWqf * PPLANE, bqf, q, nullptr, nullptr);
    hipMemsetAsync(logits, 0, (size_t)BATCH_N * 9 * sizeof(float), stream);
    mfma_gemm_k<1><<<log_grid, 256, 0, stream>>>(
        xp, 9 * 1024, 0, 1024,
        wpk + OWkf * PPLANE, bkf, nullptr, q, logits);
    softmax_cent_k<<<ew_grid, 256, 0, stream>>>(xp, logits, nullptr, out, 1);
}